// Round 4
// baseline (837.062 us; speedup 1.0000x reference)
//
#include <hip/hip_runtime.h>

// GraphSAGE 2-layer, fp32. N=100000, F_IN=64, H=128, E=1.6M.
// Round 4: replace single-pass CSR scatter (106 MB amplified writes, 146us)
// with bucketed 2-phase scatter. Phase A buckets edges by dst>>7 into packed
// u32 (localdst<<25 | src) at sequential per-bucket positions (L2-merged
// writes). Phase B sorts each bucket into its contiguous CSR segment via LDS
// cursors (writes confined to ~8KB region -> L2-merged).
// Dense layers: split-bf16 MFMA (hi+lo, 3 passes), fragment-ordered weights.

typedef __attribute__((ext_vector_type(8))) short bf16x8;  // MFMA A/B frag
typedef __attribute__((ext_vector_type(4))) float f32x4;   // MFMA C/D frag

union ABu { unsigned u[4]; bf16x8 v; };

// split 8 fp32 -> hi (bf16 trunc) + lo (bf16 of exact residual)
__device__ inline void splitA(const f32x4 fA, const f32x4 fB,
                              bf16x8& hi, bf16x8& lo) {
    ABu H, L;
    float f[8] = {fA.x, fA.y, fA.z, fA.w, fB.x, fB.y, fB.z, fB.w};
    #pragma unroll
    for (int p = 0; p < 4; ++p) {
        unsigned u0 = __float_as_uint(f[2*p]);
        unsigned u1 = __float_as_uint(f[2*p+1]);
        unsigned h0 = u0 & 0xFFFF0000u;
        unsigned h1 = u1 & 0xFFFF0000u;
        H.u[p] = (u0 >> 16) | h1;
        float r0 = f[2*p]   - __uint_as_float(h0);
        float r1 = f[2*p+1] - __uint_as_float(h1);
        L.u[p] = (__float_as_uint(r0) >> 16) | (__float_as_uint(r1) & 0xFFFF0000u);
    }
    hi = H.v; lo = L.v;
}

// ---------------- CSR build ----------------
__global__ __launch_bounds__(256) void hist_kernel(
    const int* __restrict__ ei, int* __restrict__ deg, int E)
{
    int e = blockIdx.x * 256 + threadIdx.x;
    if (e < E) atomicAdd(&deg[ei[E + e]], 1);
}

__global__ __launch_bounds__(256) void scan_reduce_kernel(
    const int* __restrict__ deg, int* __restrict__ bsum, int N)
{
    int base = blockIdx.x * 1024;
    int s = 0;
    for (int i = threadIdx.x; i < 1024; i += 256) {
        int g = base + i;
        if (g < N) s += deg[g];
    }
    __shared__ int sh[256];
    sh[threadIdx.x] = s;
    __syncthreads();
    for (int o = 128; o > 0; o >>= 1) {
        if (threadIdx.x < o) sh[threadIdx.x] += sh[threadIdx.x + o];
        __syncthreads();
    }
    if (threadIdx.x == 0) bsum[blockIdx.x] = sh[0];
}

__global__ __launch_bounds__(128) void scan_bsum_kernel(
    int* __restrict__ bsum, int nb, int* __restrict__ totalOut)
{
    __shared__ int sh[128];
    int t = threadIdx.x;
    int v = (t < nb) ? bsum[t] : 0;
    sh[t] = v;
    __syncthreads();
    for (int o = 1; o < 128; o <<= 1) {
        int a = (t >= o) ? sh[t - o] : 0;
        __syncthreads();
        sh[t] += a;
        __syncthreads();
    }
    if (t < nb) bsum[t] = sh[t] - v;
    if (t == 127) *totalOut = sh[127];
}

__global__ __launch_bounds__(256) void scan_apply_kernel(
    const int* __restrict__ deg, const int* __restrict__ bsum,
    int* __restrict__ rowptr, int N)
{
    int t = threadIdx.x;
    int g0 = blockIdx.x * 1024 + t * 4;
    int d0 = (g0 + 0 < N) ? deg[g0 + 0] : 0;
    int d1 = (g0 + 1 < N) ? deg[g0 + 1] : 0;
    int d2 = (g0 + 2 < N) ? deg[g0 + 2] : 0;
    int d3 = (g0 + 3 < N) ? deg[g0 + 3] : 0;
    int ts = d0 + d1 + d2 + d3;
    __shared__ int sh[256];
    sh[t] = ts;
    __syncthreads();
    for (int o = 1; o < 256; o <<= 1) {
        int a = (t >= o) ? sh[t - o] : 0;
        __syncthreads();
        sh[t] += a;
        __syncthreads();
    }
    int p0 = sh[t] - ts + bsum[blockIdx.x];
    int p1 = p0 + d0, p2 = p1 + d1, p3 = p2 + d2;
    if (g0 + 0 < N) rowptr[g0 + 0] = p0;
    if (g0 + 1 < N) rowptr[g0 + 1] = p1;
    if (g0 + 2 < N) rowptr[g0 + 2] = p2;
    if (g0 + 3 < N) rowptr[g0 + 3] = p3;
}

// bucket cursors start at the bucket's CSR segment base
__global__ __launch_bounds__(256) void bcur_init_kernel(
    const int* __restrict__ rowptr, int* __restrict__ bcur, int NB)
{
    int b = blockIdx.x * 256 + threadIdx.x;
    if (b < NB) bcur[b] = rowptr[b * 128];
}

// Phase A: scatter packed (localdst<<25 | src) into per-bucket sequential
// positions. Writes per bucket are cursor-sequential -> L2 line merging.
__global__ __launch_bounds__(256) void bucket_scatter_kernel(
    const int* __restrict__ ei, int* __restrict__ bcur,
    unsigned* __restrict__ pairs, int E)
{
    int e = blockIdx.x * 256 + threadIdx.x;
    if (e < E) {
        int s = ei[e];
        int d = ei[E + e];
        int b = d >> 7;
        int p = atomicAdd(&bcur[b], 1);
        pairs[p] = ((unsigned)(d & 127) << 25) | (unsigned)s;
    }
}

// Phase B: one block per bucket; LDS cursors assign final CSR positions.
// All writes land in the bucket's contiguous ssrc segment (~8KB).
__global__ __launch_bounds__(256) void bucket_sort_kernel(
    const int* __restrict__ rowptr, const unsigned* __restrict__ pairs,
    int* __restrict__ ssrc, int N)
{
    __shared__ int lcur[128];
    int nodeBase = blockIdx.x * 128;
    int nEnd = min(nodeBase + 128, N);
    int cnt = nEnd - nodeBase;
    if (threadIdx.x < cnt) lcur[threadIdx.x] = rowptr[nodeBase + threadIdx.x];
    __syncthreads();
    int segStart = rowptr[nodeBase];
    int segEnd   = rowptr[nEnd];
    for (int i = segStart + threadIdx.x; i < segEnd; i += 256) {
        unsigned p = pairs[i];
        int src = (int)(p & 0x1FFFFFFu);
        int ld  = (int)(p >> 25);
        int pos = atomicAdd(&lcur[ld], 1);
        ssrc[pos] = src;
    }
}

// ---------------- weight prep: split + fragment-order ----------------
__global__ __launch_bounds__(256) void prep_w_kernel(
    const float* __restrict__ Wl, const float* __restrict__ Wr, int F,
    short* __restrict__ w0f, short* __restrict__ w1f, int nfrag)
{
    int t = blockIdx.x * 256 + threadIdx.x;   // one thread per (frag, lane)
    if (t >= nfrag * 64) return;
    int lane = t & 63, fr = t >> 6;
    int j  = fr & 7, ks = fr >> 3;
    int col = j * 16 + (lane & 15);
    int k0  = ks * 32 + (lane >> 4) * 8;
    #pragma unroll
    for (int e = 0; e < 8; ++e) {
        int k = k0 + e;
        float w = (k < F) ? Wl[col * F + k] : Wr[col * F + (k - F)];
        unsigned u = __float_as_uint(w);
        unsigned h = u & 0xFFFF0000u;
        float r = w - __uint_as_float(h);
        w0f[t * 8 + e] = (short)(u >> 16);
        w1f[t * 8 + e] = (short)(__float_as_uint(r) >> 16);
    }
}

// ---------------- gather aggregation (writes scaled mean) ----------------
template<int F>
__global__ __launch_bounds__(256) void agg_gather_kernel(
    const int* __restrict__ rowptr, const int* __restrict__ ssrc,
    const float* __restrict__ feat, float* __restrict__ mean, int N)
{
    constexpr int V = F / 64;
    int wave = threadIdx.x >> 6;
    int lane = threadIdx.x & 63;
    int n = blockIdx.x * 4 + wave;
    if (n >= N) return;
    int rp = rowptr[n], re = rowptr[n + 1];
    float acc0 = 0.f, acc1 = 0.f;
    for (int jb = rp; jb < re; jb += 64) {
        int cnt = min(64, re - jb);
        int myidx = (lane < cnt) ? ssrc[jb + lane] : 0;
        int t = 0;
        for (; t + 4 <= cnt; t += 4) {
            int s0 = __shfl(myidx, t + 0);
            int s1 = __shfl(myidx, t + 1);
            int s2 = __shfl(myidx, t + 2);
            int s3 = __shfl(myidx, t + 3);
            if constexpr (V == 1) {
                acc0 += feat[(size_t)s0 * F + lane] + feat[(size_t)s1 * F + lane]
                      + feat[(size_t)s2 * F + lane] + feat[(size_t)s3 * F + lane];
            } else {
                float2 v0 = *reinterpret_cast<const float2*>(&feat[(size_t)s0 * F + lane * 2]);
                float2 v1 = *reinterpret_cast<const float2*>(&feat[(size_t)s1 * F + lane * 2]);
                float2 v2 = *reinterpret_cast<const float2*>(&feat[(size_t)s2 * F + lane * 2]);
                float2 v3 = *reinterpret_cast<const float2*>(&feat[(size_t)s3 * F + lane * 2]);
                acc0 += v0.x + v1.x + v2.x + v3.x;
                acc1 += v0.y + v1.y + v2.y + v3.y;
            }
        }
        for (; t < cnt; ++t) {
            int s = __shfl(myidx, t);
            if constexpr (V == 1) {
                acc0 += feat[(size_t)s * F + lane];
            } else {
                float2 v = *reinterpret_cast<const float2*>(&feat[(size_t)s * F + lane * 2]);
                acc0 += v.x; acc1 += v.y;
            }
        }
    }
    float inv = 1.0f / (float)max(re - rp, 1);
    if constexpr (V == 1) {
        mean[(size_t)n * F + lane] = acc0 * inv;
    } else {
        *reinterpret_cast<float2*>(&mean[(size_t)n * F + lane * 2]) =
            make_float2(acc0 * inv, acc1 * inv);
    }
}

// ---------------- dense layer via split-bf16 MFMA ----------------
template<int F, bool RELU>
__global__ __launch_bounds__(256, 2) void dense_mfma_kernel(
    const float* __restrict__ left,    // mean [N][F]
    const float* __restrict__ right,   // x or h [N][F]
    const short* __restrict__ w0f,     // [(2F/32)*8][64][8]
    const short* __restrict__ w1f,
    const float* __restrict__ bl,      // [128]
    float* __restrict__ out,           // [N][128]
    int N)
{
    constexpr int NS = (2 * F) / 32;   // k-steps
    const int tid  = threadIdx.x;
    const int lane = tid & 63;
    const int wv   = tid >> 6;
    const int r16  = lane & 15;
    const int kg   = lane >> 4;
    const int rowBase = blockIdx.x * 128 + wv * 32;

    const int row0 = min(rowBase + r16,      N - 1);
    const int row1 = min(rowBase + 16 + r16, N - 1);

    f32x4 acc[2][8];
    #pragma unroll
    for (int rt = 0; rt < 2; ++rt)
        #pragma unroll
        for (int j = 0; j < 8; ++j)
            acc[rt][j] = (f32x4){0.f, 0.f, 0.f, 0.f};

    #pragma unroll
    for (int ks = 0; ks < NS; ++ks) {
        const bool Lh = (ks * 32) < F;
        const float* __restrict__ src = Lh ? left : right;
        const int koff = ks * 32 - (Lh ? 0 : F) + kg * 8;

        bf16x8 a0[2], a1[2];
        {
            const float* ap0 = src + (size_t)row0 * F + koff;
            splitA(*reinterpret_cast<const f32x4*>(ap0),
                   *reinterpret_cast<const f32x4*>(ap0 + 4), a0[0], a1[0]);
            const float* ap1 = src + (size_t)row1 * F + koff;
            splitA(*reinterpret_cast<const f32x4*>(ap1),
                   *reinterpret_cast<const f32x4*>(ap1 + 4), a0[1], a1[1]);
        }

        #pragma unroll
        for (int j = 0; j < 8; ++j) {
            const size_t fb = (((size_t)(ks * 8 + j)) * 64 + lane) * 8;
            const bf16x8 b0 = *reinterpret_cast<const bf16x8*>(&w0f[fb]);
            const bf16x8 b1 = *reinterpret_cast<const bf16x8*>(&w1f[fb]);
            #pragma unroll
            for (int rt = 0; rt < 2; ++rt) {
                acc[rt][j] = __builtin_amdgcn_mfma_f32_16x16x32_bf16(
                    a0[rt], b0, acc[rt][j], 0, 0, 0);
                acc[rt][j] = __builtin_amdgcn_mfma_f32_16x16x32_bf16(
                    a0[rt], b1, acc[rt][j], 0, 0, 0);
                acc[rt][j] = __builtin_amdgcn_mfma_f32_16x16x32_bf16(
                    a1[rt], b0, acc[rt][j], 0, 0, 0);
            }
        }
    }

    #pragma unroll
    for (int j = 0; j < 8; ++j) {
        const int col = j * 16 + r16;
        const float b = bl[col];
        #pragma unroll
        for (int rt = 0; rt < 2; ++rt) {
            const int rb = rowBase + rt * 16 + kg * 4;
            #pragma unroll
            for (int i = 0; i < 4; ++i) {
                int row = rb + i;
                if (row < N) {
                    float v = acc[rt][j][i] + b;
                    if (RELU) v = fmaxf(v, 0.f);
                    out[(size_t)row * 128 + col] = v;
                }
            }
        }
    }
}

extern "C" void kernel_launch(void* const* d_in, const int* in_sizes, int n_in,
                              void* d_out, int out_size, void* d_ws, size_t ws_size,
                              hipStream_t stream) {
    const float* x   = (const float*)d_in[0];
    const int*   ei  = (const int*)d_in[1];
    const float* Wl1 = (const float*)d_in[2];
    const float* bl1 = (const float*)d_in[3];
    const float* Wr1 = (const float*)d_in[4];
    const float* Wl2 = (const float*)d_in[5];
    const float* bl2 = (const float*)d_in[6];
    const float* Wr2 = (const float*)d_in[7];
    float* out = (float*)d_out;

    const int N  = in_sizes[0] / 64;   // 100000
    const int E  = in_sizes[1] / 2;    // 1600000
    const int nb = (N + 1023) / 1024;  // scan chunks (98)
    const int NB = (N + 127) / 128;    // dst buckets (782)

    // ws layout: ints | short weight frags | floats
    int* ssrc   = (int*)d_ws;
    int* rowptr = ssrc + E;
    int* deg    = rowptr + (N + 1);
    int* bsum   = deg + N;
    int* bcur   = bsum + 128;                  // [NB] bucket cursors
    short* w0f1 = (short*)(bcur + 1024);       // 32 frags * 512
    short* w1f1 = w0f1 + 32 * 512;
    short* w0f2 = w1f1 + 32 * 512;             // 64 frags * 512
    short* w1f2 = w0f2 + 64 * 512;
    size_t shortEnd = (size_t)(w1f2 + 64 * 512 - (short*)d_ws);
    size_t floatOff = (shortEnd * 2 + 15) / 16 * 4;   // 16B-aligned float index
    float* meanbuf = (float*)d_ws + floatOff;          // [N][128]
    float* h       = meanbuf + (size_t)N * 128;        // [N][128]
    // pairs aliases meanbuf (dead until agg_gather runs, after bucket_sort)
    unsigned* pairs = (unsigned*)meanbuf;

    // CSR build
    hipMemsetAsync(deg, 0, (size_t)N * sizeof(int), stream);
    hist_kernel<<<(E + 255) / 256, 256, 0, stream>>>(ei, deg, E);
    scan_reduce_kernel<<<nb, 256, 0, stream>>>(deg, bsum, N);
    scan_bsum_kernel<<<1, 128, 0, stream>>>(bsum, nb, &rowptr[N]);
    scan_apply_kernel<<<nb, 256, 0, stream>>>(deg, bsum, rowptr, N);
    bcur_init_kernel<<<(NB + 255) / 256, 256, 0, stream>>>(rowptr, bcur, NB);
    bucket_scatter_kernel<<<(E + 255) / 256, 256, 0, stream>>>(ei, bcur, pairs, E);
    bucket_sort_kernel<<<NB, 256, 0, stream>>>(rowptr, pairs, ssrc, N);

    // weight prep (fragment-ordered split-bf16)
    prep_w_kernel<<<(32 * 64 + 255) / 256, 256, 0, stream>>>(Wl1, Wr1, 64, w0f1, w1f1, 32);
    prep_w_kernel<<<(64 * 64 + 255) / 256, 256, 0, stream>>>(Wl2, Wr2, 128, w0f2, w1f2, 64);

    const int dgrid = (N + 127) / 128;

    // layer 1
    agg_gather_kernel<64><<<(N + 3) / 4, 256, 0, stream>>>(rowptr, ssrc, x, meanbuf, N);
    dense_mfma_kernel<64, true><<<dgrid, 256, 0, stream>>>(
        meanbuf, x, w0f1, w1f1, bl1, h, N);

    // layer 2
    agg_gather_kernel<128><<<(N + 3) / 4, 256, 0, stream>>>(rowptr, ssrc, h, meanbuf, N);
    dense_mfma_kernel<128, false><<<dgrid, 256, 0, stream>>>(
        meanbuf, h, w0f2, w1f2, bl2, out, N);
}

// Round 5
// 562.611 us; speedup vs baseline: 1.4878x; 1.4878x over previous
//
#include <hip/hip_runtime.h>

// GraphSAGE 2-layer, fp32. N=100000, F_IN=64, H=128, E=1.6M.
// Round 5: atomic-free deterministic scatter. Round-4 post-mortem: 782-cursor
// global atomics serialize (~184ns each, 2046-deep chains) and cross-XCD
// same-line pair writes cost a coherent 64B round-trip (WRITE 69MB for 6.4MB).
// New pipeline: per-block LDS histogram -> deterministic 2-level scan
// (bucketBase + blockBase) -> block-owned contiguous runs (full-line writes,
// LDS-only cursors) -> per-bucket finalize builds rowptr AND sorted ssrc.
// This also deletes hist_kernel (1.6M contended atomics), 3 scan kernels, and
// the memset. Dense: split-bf16 MFMA (hi+lo, 3 passes), frag-ordered weights.

#define EPB 16384          // edges per scatter block
#define MAXNB 1024         // max dst buckets (N<=131072)

typedef __attribute__((ext_vector_type(8))) short bf16x8;  // MFMA A/B frag
typedef __attribute__((ext_vector_type(4))) float f32x4;   // MFMA C/D frag

union ABu { unsigned u[4]; bf16x8 v; };

// split 8 fp32 -> hi (bf16 trunc) + lo (bf16 of exact residual)
__device__ inline void splitA(const f32x4 fA, const f32x4 fB,
                              bf16x8& hi, bf16x8& lo) {
    ABu H, L;
    float f[8] = {fA.x, fA.y, fA.z, fA.w, fB.x, fB.y, fB.z, fB.w};
    #pragma unroll
    for (int p = 0; p < 4; ++p) {
        unsigned u0 = __float_as_uint(f[2*p]);
        unsigned u1 = __float_as_uint(f[2*p+1]);
        unsigned h0 = u0 & 0xFFFF0000u;
        unsigned h1 = u1 & 0xFFFF0000u;
        H.u[p] = (u0 >> 16) | h1;
        float r0 = f[2*p]   - __uint_as_float(h0);
        float r1 = f[2*p+1] - __uint_as_float(h1);
        L.u[p] = (__float_as_uint(r0) >> 16) | (__float_as_uint(r1) & 0xFFFF0000u);
    }
    hi = H.v; lo = L.v;
}

// ---------------- step 1: per-block bucket histogram ----------------
__global__ __launch_bounds__(256) void count_blocks_kernel(
    const int* __restrict__ ei, int* __restrict__ blockCounts, // [NB][NBLK]
    int E, int NB, int NBLK)
{
    __shared__ int hist[MAXNB];
    for (int i = threadIdx.x; i < NB; i += 256) hist[i] = 0;
    __syncthreads();
    int e0 = blockIdx.x * EPB;
    int e1 = min(e0 + EPB, E);
    for (int e = e0 + threadIdx.x; e < e1; e += 256)
        atomicAdd(&hist[ei[E + e] >> 7], 1);
    __syncthreads();
    for (int i = threadIdx.x; i < NB; i += 256)
        blockCounts[i * NBLK + blockIdx.x] = hist[i];
}

// ---------------- step 2: deterministic 2-level scan ----------------
// one block: bucket totals -> exclusive scan -> bucketBase; per-bucket
// running prefix over blocks -> blockBase. NB <= 1024 required.
__global__ __launch_bounds__(1024) void scan_buckets_kernel(
    const int* __restrict__ blockCounts,   // [NB][NBLK]
    int* __restrict__ blockBase,           // [NB][NBLK]
    int* __restrict__ bucketBase,          // [NB+1]
    int NB, int NBLK)
{
    __shared__ int tot[1024];
    int t = threadIdx.x;
    int total = 0;
    if (t < NB) {
        const int* col = &blockCounts[t * NBLK];
        for (int k = 0; k < NBLK; ++k) total += col[k];
    }
    tot[t] = total;
    __syncthreads();
    for (int o = 1; o < 1024; o <<= 1) {
        int a = (t >= o) ? tot[t - o] : 0;
        __syncthreads();
        tot[t] += a;
        __syncthreads();
    }
    if (t < NB) {
        int base = tot[t] - total;        // exclusive prefix
        bucketBase[t] = base;
        const int* col = &blockCounts[t * NBLK];
        int* ob = &blockBase[t * NBLK];
        int run = base;
        for (int k = 0; k < NBLK; ++k) { ob[k] = run; run += col[k]; }
    }
    if (t == 0) bucketBase[NB] = tot[1023];   // == E
}

// ---------------- step 3: write pairs into block-owned runs ----------------
__global__ __launch_bounds__(256) void write_pairs_kernel(
    const int* __restrict__ ei, const int* __restrict__ blockBase,
    unsigned* __restrict__ pairs, int E, int NB, int NBLK)
{
    __shared__ int cur[MAXNB];
    for (int i = threadIdx.x; i < NB; i += 256)
        cur[i] = blockBase[i * NBLK + blockIdx.x];
    __syncthreads();
    int e0 = blockIdx.x * EPB;
    int e1 = min(e0 + EPB, E);
    for (int e = e0 + threadIdx.x; e < e1; e += 256) {
        int s = ei[e];
        int d = ei[E + e];
        int p = atomicAdd(&cur[d >> 7], 1);      // LDS atomic, ~21-deep
        pairs[p] = ((unsigned)(d & 127) << 25) | (unsigned)s;
    }
}

// ---------------- step 4: per-bucket finalize: rowptr + sorted ssrc --------
__global__ __launch_bounds__(256) void bucket_finalize_kernel(
    const unsigned* __restrict__ pairs, const int* __restrict__ bucketBase,
    int* __restrict__ rowptr, int* __restrict__ ssrc, int N)
{
    __shared__ int hist[128];
    __shared__ int scn[128];
    __shared__ int cur[128];
    int t = threadIdx.x;
    int b = blockIdx.x;
    int segS = bucketBase[b], segE = bucketBase[b + 1];
    if (t < 128) hist[t] = 0;
    __syncthreads();
    for (int i = segS + t; i < segE; i += 256)
        atomicAdd(&hist[pairs[i] >> 25], 1);
    __syncthreads();
    if (t < 128) scn[t] = hist[t];
    __syncthreads();
    for (int o = 1; o < 128; o <<= 1) {
        int a = 0;
        if (t < 128 && t >= o) a = scn[t - o];
        __syncthreads();
        if (t < 128) scn[t] += a;
        __syncthreads();
    }
    if (t < 128) {
        int start = segS + scn[t] - hist[t];     // exclusive prefix
        cur[t] = start;
        int node = b * 128 + t;
        if (node < N) rowptr[node] = start;
    }
    if (b == 0 && t == 0) rowptr[N] = bucketBase[gridDim.x];
    __syncthreads();
    for (int i = segS + t; i < segE; i += 256) {
        unsigned p = pairs[i];
        int pos = atomicAdd(&cur[p >> 25], 1);
        ssrc[pos] = (int)(p & 0x1FFFFFFu);
    }
}

// ---------------- weight prep: split + fragment-order ----------------
__global__ __launch_bounds__(256) void prep_w_kernel(
    const float* __restrict__ Wl, const float* __restrict__ Wr, int F,
    short* __restrict__ w0f, short* __restrict__ w1f, int nfrag)
{
    int t = blockIdx.x * 256 + threadIdx.x;   // one thread per (frag, lane)
    if (t >= nfrag * 64) return;
    int lane = t & 63, fr = t >> 6;
    int j  = fr & 7, ks = fr >> 3;
    int col = j * 16 + (lane & 15);
    int k0  = ks * 32 + (lane >> 4) * 8;
    #pragma unroll
    for (int e = 0; e < 8; ++e) {
        int k = k0 + e;
        float w = (k < F) ? Wl[col * F + k] : Wr[col * F + (k - F)];
        unsigned u = __float_as_uint(w);
        unsigned h = u & 0xFFFF0000u;
        float r = w - __uint_as_float(h);
        w0f[t * 8 + e] = (short)(u >> 16);
        w1f[t * 8 + e] = (short)(__float_as_uint(r) >> 16);
    }
}

// ---------------- gather aggregation (writes scaled mean) ----------------
template<int F>
__global__ __launch_bounds__(256) void agg_gather_kernel(
    const int* __restrict__ rowptr, const int* __restrict__ ssrc,
    const float* __restrict__ feat, float* __restrict__ mean, int N)
{
    constexpr int V = F / 64;
    int wave = threadIdx.x >> 6;
    int lane = threadIdx.x & 63;
    int n = blockIdx.x * 4 + wave;
    if (n >= N) return;
    int rp = rowptr[n], re = rowptr[n + 1];
    float acc0 = 0.f, acc1 = 0.f;
    for (int jb = rp; jb < re; jb += 64) {
        int cnt = min(64, re - jb);
        int myidx = (lane < cnt) ? ssrc[jb + lane] : 0;
        int t = 0;
        for (; t + 4 <= cnt; t += 4) {
            int s0 = __shfl(myidx, t + 0);
            int s1 = __shfl(myidx, t + 1);
            int s2 = __shfl(myidx, t + 2);
            int s3 = __shfl(myidx, t + 3);
            if constexpr (V == 1) {
                acc0 += feat[(size_t)s0 * F + lane] + feat[(size_t)s1 * F + lane]
                      + feat[(size_t)s2 * F + lane] + feat[(size_t)s3 * F + lane];
            } else {
                float2 v0 = *reinterpret_cast<const float2*>(&feat[(size_t)s0 * F + lane * 2]);
                float2 v1 = *reinterpret_cast<const float2*>(&feat[(size_t)s1 * F + lane * 2]);
                float2 v2 = *reinterpret_cast<const float2*>(&feat[(size_t)s2 * F + lane * 2]);
                float2 v3 = *reinterpret_cast<const float2*>(&feat[(size_t)s3 * F + lane * 2]);
                acc0 += v0.x + v1.x + v2.x + v3.x;
                acc1 += v0.y + v1.y + v2.y + v3.y;
            }
        }
        for (; t < cnt; ++t) {
            int s = __shfl(myidx, t);
            if constexpr (V == 1) {
                acc0 += feat[(size_t)s * F + lane];
            } else {
                float2 v = *reinterpret_cast<const float2*>(&feat[(size_t)s * F + lane * 2]);
                acc0 += v.x; acc1 += v.y;
            }
        }
    }
    float inv = 1.0f / (float)max(re - rp, 1);
    if constexpr (V == 1) {
        mean[(size_t)n * F + lane] = acc0 * inv;
    } else {
        *reinterpret_cast<float2*>(&mean[(size_t)n * F + lane * 2]) =
            make_float2(acc0 * inv, acc1 * inv);
    }
}

// ---------------- dense layer via split-bf16 MFMA ----------------
template<int F, bool RELU>
__global__ __launch_bounds__(256, 2) void dense_mfma_kernel(
    const float* __restrict__ left,    // mean [N][F]
    const float* __restrict__ right,   // x or h [N][F]
    const short* __restrict__ w0f,     // [(2F/32)*8][64][8]
    const short* __restrict__ w1f,
    const float* __restrict__ bl,      // [128]
    float* __restrict__ out,           // [N][128]
    int N)
{
    constexpr int NS = (2 * F) / 32;   // k-steps
    const int tid  = threadIdx.x;
    const int lane = tid & 63;
    const int wv   = tid >> 6;
    const int r16  = lane & 15;
    const int kg   = lane >> 4;
    const int rowBase = blockIdx.x * 128 + wv * 32;

    const int row0 = min(rowBase + r16,      N - 1);
    const int row1 = min(rowBase + 16 + r16, N - 1);

    f32x4 acc[2][8];
    #pragma unroll
    for (int rt = 0; rt < 2; ++rt)
        #pragma unroll
        for (int j = 0; j < 8; ++j)
            acc[rt][j] = (f32x4){0.f, 0.f, 0.f, 0.f};

    #pragma unroll
    for (int ks = 0; ks < NS; ++ks) {
        const bool Lh = (ks * 32) < F;
        const float* __restrict__ src = Lh ? left : right;
        const int koff = ks * 32 - (Lh ? 0 : F) + kg * 8;

        bf16x8 a0[2], a1[2];
        {
            const float* ap0 = src + (size_t)row0 * F + koff;
            splitA(*reinterpret_cast<const f32x4*>(ap0),
                   *reinterpret_cast<const f32x4*>(ap0 + 4), a0[0], a1[0]);
            const float* ap1 = src + (size_t)row1 * F + koff;
            splitA(*reinterpret_cast<const f32x4*>(ap1),
                   *reinterpret_cast<const f32x4*>(ap1 + 4), a0[1], a1[1]);
        }

        #pragma unroll
        for (int j = 0; j < 8; ++j) {
            const size_t fb = (((size_t)(ks * 8 + j)) * 64 + lane) * 8;
            const bf16x8 b0 = *reinterpret_cast<const bf16x8*>(&w0f[fb]);
            const bf16x8 b1 = *reinterpret_cast<const bf16x8*>(&w1f[fb]);
            #pragma unroll
            for (int rt = 0; rt < 2; ++rt) {
                acc[rt][j] = __builtin_amdgcn_mfma_f32_16x16x32_bf16(
                    a0[rt], b0, acc[rt][j], 0, 0, 0);
                acc[rt][j] = __builtin_amdgcn_mfma_f32_16x16x32_bf16(
                    a0[rt], b1, acc[rt][j], 0, 0, 0);
                acc[rt][j] = __builtin_amdgcn_mfma_f32_16x16x32_bf16(
                    a1[rt], b0, acc[rt][j], 0, 0, 0);
            }
        }
    }

    #pragma unroll
    for (int j = 0; j < 8; ++j) {
        const int col = j * 16 + r16;
        const float b = bl[col];
        #pragma unroll
        for (int rt = 0; rt < 2; ++rt) {
            const int rb = rowBase + rt * 16 + kg * 4;
            #pragma unroll
            for (int i = 0; i < 4; ++i) {
                int row = rb + i;
                if (row < N) {
                    float v = acc[rt][j][i] + b;
                    if (RELU) v = fmaxf(v, 0.f);
                    out[(size_t)row * 128 + col] = v;
                }
            }
        }
    }
}

extern "C" void kernel_launch(void* const* d_in, const int* in_sizes, int n_in,
                              void* d_out, int out_size, void* d_ws, size_t ws_size,
                              hipStream_t stream) {
    const float* x   = (const float*)d_in[0];
    const int*   ei  = (const int*)d_in[1];
    const float* Wl1 = (const float*)d_in[2];
    const float* bl1 = (const float*)d_in[3];
    const float* Wr1 = (const float*)d_in[4];
    const float* Wl2 = (const float*)d_in[5];
    const float* bl2 = (const float*)d_in[6];
    const float* Wr2 = (const float*)d_in[7];
    float* out = (float*)d_out;

    const int N    = in_sizes[0] / 64;     // 100000
    const int E    = in_sizes[1] / 2;      // 1600000
    const int NB   = (N + 127) / 128;      // dst buckets (782)
    const int NBLK = (E + EPB - 1) / EPB;  // scatter blocks (98)

    // ws layout: ints | short weight frags | floats
    int* ssrc       = (int*)d_ws;
    int* rowptr     = ssrc + E;                  // [N+1]
    int* bucketBase = rowptr + (N + 1);          // [NB+1]
    int* blockCounts= bucketBase + (NB + 1);     // [NB*NBLK]
    int* blockBase  = blockCounts + NB * NBLK;   // [NB*NBLK]
    short* w0f1 = (short*)(blockBase + NB * NBLK);   // 32 frags * 512
    short* w1f1 = w0f1 + 32 * 512;
    short* w0f2 = w1f1 + 32 * 512;                   // 64 frags * 512
    short* w1f2 = w0f2 + 64 * 512;
    size_t shortEnd = (size_t)(w1f2 + 64 * 512 - (short*)d_ws);
    size_t floatOff = (shortEnd * 2 + 15) / 16 * 4;  // 16B-aligned float index
    float* meanbuf = (float*)d_ws + floatOff;        // [N][128]
    float* h       = meanbuf + (size_t)N * 128;      // [N][128]
    // pairs aliases meanbuf (dead before agg_gather writes meanbuf)
    unsigned* pairs = (unsigned*)meanbuf;

    // atomic-free CSR build
    count_blocks_kernel<<<NBLK, 256, 0, stream>>>(ei, blockCounts, E, NB, NBLK);
    scan_buckets_kernel<<<1, 1024, 0, stream>>>(blockCounts, blockBase, bucketBase, NB, NBLK);
    write_pairs_kernel<<<NBLK, 256, 0, stream>>>(ei, blockBase, pairs, E, NB, NBLK);
    bucket_finalize_kernel<<<NB, 256, 0, stream>>>(pairs, bucketBase, rowptr, ssrc, N);

    // weight prep (fragment-ordered split-bf16)
    prep_w_kernel<<<(32 * 64 + 255) / 256, 256, 0, stream>>>(Wl1, Wr1, 64, w0f1, w1f1, 32);
    prep_w_kernel<<<(64 * 64 + 255) / 256, 256, 0, stream>>>(Wl2, Wr2, 128, w0f2, w1f2, 64);

    const int dgrid = (N + 127) / 128;

    // layer 1
    agg_gather_kernel<64><<<(N + 3) / 4, 256, 0, stream>>>(rowptr, ssrc, x, meanbuf, N);
    dense_mfma_kernel<64, true><<<dgrid, 256, 0, stream>>>(
        meanbuf, x, w0f1, w1f1, bl1, h, N);

    // layer 2
    agg_gather_kernel<128><<<(N + 3) / 4, 256, 0, stream>>>(rowptr, ssrc, h, meanbuf, N);
    dense_mfma_kernel<128, false><<<dgrid, 256, 0, stream>>>(
        meanbuf, h, w0f2, w1f2, bl2, out, N);
}

// Round 6
// 440.348 us; speedup vs baseline: 1.9009x; 1.2777x over previous
//
#include <hip/hip_runtime.h>

// GraphSAGE 2-layer, fp32. N=100000, F_IN=64, H=128, E=1.6M.
// Round 6: gather was at the ~6.3 TB/s memory ceiling for fp32 rows
// (877 MB logical in 140us). Halve gathered bytes: aggregate from bf16 (RNE)
// copies of x and h; accumulate fp32; mean stays fp32. Dense layers keep
// fp32 inputs (hi+lo split MFMA) — only the aggregation path is rounded.
// Lane remap: 8B chunk per lane -> G=2/4 edges per wave-load (more MLP).
// scan_buckets: [blk][bucket] layout for coalesced single-block scan.
// hb aliases d_out; xb aliases upper meanbuf region (no ws growth).

#define EPB 16384          // edges per scatter block
#define MAXNB 1024         // max dst buckets (N<=131072)

typedef __attribute__((ext_vector_type(8))) short bf16x8;  // MFMA A/B frag
typedef __attribute__((ext_vector_type(4))) float f32x4;   // MFMA C/D frag

union ABu { unsigned u[4]; bf16x8 v; };

__device__ inline unsigned short f2bf_rne(float f) {
    unsigned u = __float_as_uint(f);
    return (unsigned short)((u + 0x7FFFu + ((u >> 16) & 1u)) >> 16);
}
__device__ inline float bf2f(unsigned short b) {
    return __uint_as_float((unsigned)b << 16);
}

// split 8 fp32 -> hi (bf16 trunc) + lo (bf16 of exact residual)
__device__ inline void splitA(const f32x4 fA, const f32x4 fB,
                              bf16x8& hi, bf16x8& lo) {
    ABu H, L;
    float f[8] = {fA.x, fA.y, fA.z, fA.w, fB.x, fB.y, fB.z, fB.w};
    #pragma unroll
    for (int p = 0; p < 4; ++p) {
        unsigned u0 = __float_as_uint(f[2*p]);
        unsigned u1 = __float_as_uint(f[2*p+1]);
        unsigned h0 = u0 & 0xFFFF0000u;
        unsigned h1 = u1 & 0xFFFF0000u;
        H.u[p] = (u0 >> 16) | h1;
        float r0 = f[2*p]   - __uint_as_float(h0);
        float r1 = f[2*p+1] - __uint_as_float(h1);
        L.u[p] = (__float_as_uint(r0) >> 16) | (__float_as_uint(r1) & 0xFFFF0000u);
    }
    hi = H.v; lo = L.v;
}

// ---------------- fp32 -> bf16 (RNE) bulk convert ----------------
__global__ __launch_bounds__(256) void cvt_bf16_kernel(
    const float* __restrict__ in, unsigned short* __restrict__ out, int n)
{
    int i = (blockIdx.x * 256 + threadIdx.x) * 4;
    if (i >= n) return;
    float4 v = *reinterpret_cast<const float4*>(&in[i]);
    ushort4 o;
    o.x = f2bf_rne(v.x); o.y = f2bf_rne(v.y);
    o.z = f2bf_rne(v.z); o.w = f2bf_rne(v.w);
    *reinterpret_cast<ushort4*>(&out[i]) = o;
}

// ---------------- step 1: per-block bucket histogram ----------------
__global__ __launch_bounds__(256) void count_blocks_kernel(
    const int* __restrict__ ei, int* __restrict__ blockCounts, // [NBLK][NB]
    int E, int NB)
{
    __shared__ int hist[MAXNB];
    for (int i = threadIdx.x; i < NB; i += 256) hist[i] = 0;
    __syncthreads();
    int e0 = blockIdx.x * EPB;
    int e1 = min(e0 + EPB, E);
    for (int e = e0 + threadIdx.x; e < e1; e += 256)
        atomicAdd(&hist[ei[E + e] >> 7], 1);
    __syncthreads();
    for (int i = threadIdx.x; i < NB; i += 256)
        blockCounts[blockIdx.x * NB + i] = hist[i];
}

// ---------------- step 2: deterministic 2-level scan ----------------
// [blk][bucket] layout: all k-loop accesses coalesced across threads.
__global__ __launch_bounds__(1024) void scan_buckets_kernel(
    const int* __restrict__ blockCounts,   // [NBLK][NB]
    int* __restrict__ blockBase,           // [NBLK][NB]
    int* __restrict__ bucketBase,          // [NB+1]
    int NB, int NBLK)
{
    __shared__ int tot[1024];
    int t = threadIdx.x;
    int run = 0;
    if (t < NB) {
        for (int k = 0; k < NBLK; ++k) {
            int c = blockCounts[k * NB + t];
            blockBase[k * NB + t] = run;   // prefix within bucket
            run += c;
        }
    }
    tot[t] = run;
    __syncthreads();
    for (int o = 1; o < 1024; o <<= 1) {
        int a = (t >= o) ? tot[t - o] : 0;
        __syncthreads();
        tot[t] += a;
        __syncthreads();
    }
    if (t < NB) {
        int base = tot[t] - run;           // exclusive prefix
        bucketBase[t] = base;
        for (int k = 0; k < NBLK; ++k) blockBase[k * NB + t] += base;
    }
    if (t == 0) bucketBase[NB] = tot[1023];   // == E
}

// ---------------- step 3: write pairs into block-owned runs ----------------
__global__ __launch_bounds__(256) void write_pairs_kernel(
    const int* __restrict__ ei, const int* __restrict__ blockBase,
    unsigned* __restrict__ pairs, int E, int NB)
{
    __shared__ int cur[MAXNB];
    for (int i = threadIdx.x; i < NB; i += 256)
        cur[i] = blockBase[blockIdx.x * NB + i];
    __syncthreads();
    int e0 = blockIdx.x * EPB;
    int e1 = min(e0 + EPB, E);
    for (int e = e0 + threadIdx.x; e < e1; e += 256) {
        int s = ei[e];
        int d = ei[E + e];
        int p = atomicAdd(&cur[d >> 7], 1);      // LDS atomic, ~21-deep
        pairs[p] = ((unsigned)(d & 127) << 25) | (unsigned)s;
    }
}

// ---------------- step 4: per-bucket finalize: rowptr + sorted ssrc --------
__global__ __launch_bounds__(256) void bucket_finalize_kernel(
    const unsigned* __restrict__ pairs, const int* __restrict__ bucketBase,
    int* __restrict__ rowptr, int* __restrict__ ssrc, int N)
{
    __shared__ int hist[128];
    __shared__ int scn[128];
    __shared__ int cur[128];
    int t = threadIdx.x;
    int b = blockIdx.x;
    int segS = bucketBase[b], segE = bucketBase[b + 1];
    if (t < 128) hist[t] = 0;
    __syncthreads();
    for (int i = segS + t; i < segE; i += 256)
        atomicAdd(&hist[pairs[i] >> 25], 1);
    __syncthreads();
    if (t < 128) scn[t] = hist[t];
    __syncthreads();
    for (int o = 1; o < 128; o <<= 1) {
        int a = 0;
        if (t < 128 && t >= o) a = scn[t - o];
        __syncthreads();
        if (t < 128) scn[t] += a;
        __syncthreads();
    }
    if (t < 128) {
        int start = segS + scn[t] - hist[t];     // exclusive prefix
        cur[t] = start;
        int node = b * 128 + t;
        if (node < N) rowptr[node] = start;
    }
    if (b == 0 && t == 0) rowptr[N] = bucketBase[gridDim.x];
    __syncthreads();
    for (int i = segS + t; i < segE; i += 256) {
        unsigned p = pairs[i];
        int pos = atomicAdd(&cur[p >> 25], 1);
        ssrc[pos] = (int)(p & 0x1FFFFFFu);
    }
}

// ---------------- weight prep: split + fragment-order ----------------
__global__ __launch_bounds__(256) void prep_w_kernel(
    const float* __restrict__ Wl, const float* __restrict__ Wr, int F,
    short* __restrict__ w0f, short* __restrict__ w1f, int nfrag)
{
    int t = blockIdx.x * 256 + threadIdx.x;   // one thread per (frag, lane)
    if (t >= nfrag * 64) return;
    int lane = t & 63, fr = t >> 6;
    int j  = fr & 7, ks = fr >> 3;
    int col = j * 16 + (lane & 15);
    int k0  = ks * 32 + (lane >> 4) * 8;
    #pragma unroll
    for (int e = 0; e < 8; ++e) {
        int k = k0 + e;
        float w = (k < F) ? Wl[col * F + k] : Wr[col * F + (k - F)];
        unsigned u = __float_as_uint(w);
        unsigned h = u & 0xFFFF0000u;
        float r = w - __uint_as_float(h);
        w0f[t * 8 + e] = (short)(u >> 16);
        w1f[t * 8 + e] = (short)(__float_as_uint(r) >> 16);
    }
}

// ---------------- gather aggregation from bf16 rows ----------------
// Lane covers an 8B chunk (4 feats). G = 64/C edges per wave-load.
// Cross-group shfl_xor reduce at the end; lanes 0..C-1 write float4 mean.
template<int F>
__global__ __launch_bounds__(256) void agg_gather_kernel(
    const int* __restrict__ rowptr, const int* __restrict__ ssrc,
    const unsigned short* __restrict__ feat,   // [N][F] bf16
    float* __restrict__ mean, int N)           // [N][F] fp32
{
    constexpr int C = F / 4;        // chunks per row (8B each)
    constexpr int G = 64 / C;       // edges per wave-load
    int wave = threadIdx.x >> 6;
    int lane = threadIdx.x & 63;
    int n = blockIdx.x * 4 + wave;
    if (n >= N) return;
    int rp = rowptr[n], re = rowptr[n + 1];
    const int chunk = lane & (C - 1);
    const int grp   = lane / C;
    float a0 = 0.f, a1 = 0.f, a2 = 0.f, a3 = 0.f;

    for (int jb = rp; jb < re; jb += 64) {
        int cnt = min(64, re - jb);
        int myidx = (lane < cnt) ? ssrc[jb + lane] : 0;
        int steps = (cnt + G - 1) / G;
        int t = 0;
        for (; t + 4 <= steps; t += 4) {
            int s[4]; bool v[4];
            #pragma unroll
            for (int i = 0; i < 4; ++i) {
                int e = (t + i) * G + grp;
                s[i] = __shfl(myidx, e);
                v[i] = e < cnt;
            }
            #pragma unroll
            for (int i = 0; i < 4; ++i) {
                if (v[i]) {
                    ushort4 u = *reinterpret_cast<const ushort4*>(
                        &feat[(size_t)s[i] * F + chunk * 4]);
                    a0 += bf2f(u.x); a1 += bf2f(u.y);
                    a2 += bf2f(u.z); a3 += bf2f(u.w);
                }
            }
        }
        for (; t < steps; ++t) {
            int e = t * G + grp;
            int s = __shfl(myidx, e);
            if (e < cnt) {
                ushort4 u = *reinterpret_cast<const ushort4*>(
                    &feat[(size_t)s * F + chunk * 4]);
                a0 += bf2f(u.x); a1 += bf2f(u.y);
                a2 += bf2f(u.z); a3 += bf2f(u.w);
            }
        }
    }

    // reduce across the G lane-groups
    #pragma unroll
    for (int o = C; o < 64; o <<= 1) {
        a0 += __shfl_xor(a0, o);
        a1 += __shfl_xor(a1, o);
        a2 += __shfl_xor(a2, o);
        a3 += __shfl_xor(a3, o);
    }
    if (lane < C) {
        float inv = 1.0f / (float)max(re - rp, 1);
        float4 o4 = make_float4(a0 * inv, a1 * inv, a2 * inv, a3 * inv);
        *reinterpret_cast<float4*>(&mean[(size_t)n * F + lane * 4]) = o4;
    }
}

// ---------------- dense layer via split-bf16 MFMA ----------------
template<int F, bool RELU, bool EMIT_BF16>
__global__ __launch_bounds__(256, 2) void dense_mfma_kernel(
    const float* __restrict__ left,    // mean [N][F]
    const float* __restrict__ right,   // x or h [N][F]
    const short* __restrict__ w0f,     // [(2F/32)*8][64][8]
    const short* __restrict__ w1f,
    const float* __restrict__ bl,      // [128]
    float* __restrict__ out,           // [N][128]
    unsigned short* __restrict__ outb, // [N][128] bf16 (EMIT_BF16 only)
    int N)
{
    constexpr int NS = (2 * F) / 32;   // k-steps
    const int tid  = threadIdx.x;
    const int lane = tid & 63;
    const int wv   = tid >> 6;
    const int r16  = lane & 15;
    const int kg   = lane >> 4;
    const int rowBase = blockIdx.x * 128 + wv * 32;

    const int row0 = min(rowBase + r16,      N - 1);
    const int row1 = min(rowBase + 16 + r16, N - 1);

    f32x4 acc[2][8];
    #pragma unroll
    for (int rt = 0; rt < 2; ++rt)
        #pragma unroll
        for (int j = 0; j < 8; ++j)
            acc[rt][j] = (f32x4){0.f, 0.f, 0.f, 0.f};

    #pragma unroll
    for (int ks = 0; ks < NS; ++ks) {
        const bool Lh = (ks * 32) < F;
        const float* __restrict__ src = Lh ? left : right;
        const int koff = ks * 32 - (Lh ? 0 : F) + kg * 8;

        bf16x8 a0[2], a1[2];
        {
            const float* ap0 = src + (size_t)row0 * F + koff;
            splitA(*reinterpret_cast<const f32x4*>(ap0),
                   *reinterpret_cast<const f32x4*>(ap0 + 4), a0[0], a1[0]);
            const float* ap1 = src + (size_t)row1 * F + koff;
            splitA(*reinterpret_cast<const f32x4*>(ap1),
                   *reinterpret_cast<const f32x4*>(ap1 + 4), a0[1], a1[1]);
        }

        #pragma unroll
        for (int j = 0; j < 8; ++j) {
            const size_t fb = (((size_t)(ks * 8 + j)) * 64 + lane) * 8;
            const bf16x8 b0 = *reinterpret_cast<const bf16x8*>(&w0f[fb]);
            const bf16x8 b1 = *reinterpret_cast<const bf16x8*>(&w1f[fb]);
            #pragma unroll
            for (int rt = 0; rt < 2; ++rt) {
                acc[rt][j] = __builtin_amdgcn_mfma_f32_16x16x32_bf16(
                    a0[rt], b0, acc[rt][j], 0, 0, 0);
                acc[rt][j] = __builtin_amdgcn_mfma_f32_16x16x32_bf16(
                    a0[rt], b1, acc[rt][j], 0, 0, 0);
                acc[rt][j] = __builtin_amdgcn_mfma_f32_16x16x32_bf16(
                    a1[rt], b0, acc[rt][j], 0, 0, 0);
            }
        }
    }

    #pragma unroll
    for (int j = 0; j < 8; ++j) {
        const int col = j * 16 + r16;
        const float b = bl[col];
        #pragma unroll
        for (int rt = 0; rt < 2; ++rt) {
            const int rb = rowBase + rt * 16 + kg * 4;
            #pragma unroll
            for (int i = 0; i < 4; ++i) {
                int row = rb + i;
                if (row < N) {
                    float v = acc[rt][j][i] + b;
                    if (RELU) v = fmaxf(v, 0.f);
                    out[(size_t)row * 128 + col] = v;
                    if (EMIT_BF16) outb[(size_t)row * 128 + col] = f2bf_rne(v);
                }
            }
        }
    }
}

extern "C" void kernel_launch(void* const* d_in, const int* in_sizes, int n_in,
                              void* d_out, int out_size, void* d_ws, size_t ws_size,
                              hipStream_t stream) {
    const float* x   = (const float*)d_in[0];
    const int*   ei  = (const int*)d_in[1];
    const float* Wl1 = (const float*)d_in[2];
    const float* bl1 = (const float*)d_in[3];
    const float* Wr1 = (const float*)d_in[4];
    const float* Wl2 = (const float*)d_in[5];
    const float* bl2 = (const float*)d_in[6];
    const float* Wr2 = (const float*)d_in[7];
    float* out = (float*)d_out;

    const int N    = in_sizes[0] / 64;     // 100000
    const int E    = in_sizes[1] / 2;      // 1600000
    const int NB   = (N + 127) / 128;      // dst buckets (782)
    const int NBLK = (E + EPB - 1) / EPB;  // scatter blocks (98)

    // ws layout: ints | short weight frags | floats
    int* ssrc       = (int*)d_ws;
    int* rowptr     = ssrc + E;                  // [N+1]
    int* bucketBase = rowptr + (N + 1);          // [NB+1]
    int* blockCounts= bucketBase + (NB + 1);     // [NBLK*NB]
    int* blockBase  = blockCounts + NB * NBLK;   // [NBLK*NB]
    short* w0f1 = (short*)(blockBase + NB * NBLK);   // 32 frags * 512
    short* w1f1 = w0f1 + 32 * 512;
    short* w0f2 = w1f1 + 32 * 512;                   // 64 frags * 512
    short* w1f2 = w0f2 + 64 * 512;
    size_t shortEnd = (size_t)(w1f2 + 64 * 512 - (short*)d_ws);
    size_t floatOff = (shortEnd * 2 + 15) / 16 * 4;  // 16B-aligned float index
    float* meanbuf = (float*)d_ws + floatOff;        // [N][128]
    float* h       = meanbuf + (size_t)N * 128;      // [N][128]
    // aliases (disjoint in time):
    //   pairs = meanbuf[0 : E]            (dead before gather1 writes mean64)
    //   xb    = meanbuf[8M : 8M+6.4M]     (ushort; dead before gather2's mean128)
    //   hb    = d_out                      (dead before dense2 writes out)
    unsigned* pairs     = (unsigned*)meanbuf;
    unsigned short* xb  = (unsigned short*)(meanbuf + 8000000);
    unsigned short* hb  = (unsigned short*)d_out;

    // bf16 copy of x for gather1
    cvt_bf16_kernel<<<(N * 64 / 4 + 255) / 256, 256, 0, stream>>>(x, xb, N * 64);

    // atomic-free CSR build
    count_blocks_kernel<<<NBLK, 256, 0, stream>>>(ei, blockCounts, E, NB);
    scan_buckets_kernel<<<1, 1024, 0, stream>>>(blockCounts, blockBase, bucketBase, NB, NBLK);
    write_pairs_kernel<<<NBLK, 256, 0, stream>>>(ei, blockBase, pairs, E, NB);
    bucket_finalize_kernel<<<NB, 256, 0, stream>>>(pairs, bucketBase, rowptr, ssrc, N);

    // weight prep (fragment-ordered split-bf16)
    prep_w_kernel<<<(32 * 64 + 255) / 256, 256, 0, stream>>>(Wl1, Wr1, 64, w0f1, w1f1, 32);
    prep_w_kernel<<<(64 * 64 + 255) / 256, 256, 0, stream>>>(Wl2, Wr2, 128, w0f2, w1f2, 64);

    const int dgrid = (N + 127) / 128;

    // layer 1: gather bf16(x) -> mean64; dense emits h fp32 + hb bf16
    agg_gather_kernel<64><<<(N + 3) / 4, 256, 0, stream>>>(rowptr, ssrc, xb, meanbuf, N);
    dense_mfma_kernel<64, true, true><<<dgrid, 256, 0, stream>>>(
        meanbuf, x, w0f1, w1f1, bl1, h, hb, N);

    // layer 2: gather bf16(h) -> mean128; dense writes final out
    agg_gather_kernel<128><<<(N + 3) / 4, 256, 0, stream>>>(rowptr, ssrc, hb, meanbuf, N);
    dense_mfma_kernel<128, false, false><<<dgrid, 256, 0, stream>>>(
        meanbuf, h, w0f2, w1f2, bl2, out, nullptr, N);
}